// Round 5
// baseline (216.085 us; speedup 1.0000x reference)
//
#include <hip/hip_runtime.h>

typedef unsigned int u32;

static constexpr int HH = 1080, WW = 1920;
static constexpr int NPIX = HH * WW;           // 2,073,600
static constexpr int NQ = 17;                  // supports split <= 16 (actual 10)
static constexpr int NBLK_A = 256;             // grid-stride blocks for level-1 pass
static constexpr int R1 = 16;                  // replicas for level-1 bin merge
static constexpr int TS = 64;                  // target tile size
static constexpr int TCX = WW / TS;            // 30
static constexpr int TCY = (HH + TS - 1) / TS; // 17
static constexpr int NTILE = TCX * TCY;        // 510 (padded to 512)
static constexpr int CUR_STRIDE = 16;          // cursor padding (1 per cache line)

// ---- workspace layout (bytes) ----
static constexpr size_t MIDS_OFF  = 0;       // float[32]
static constexpr size_t QB1_OFF   = 128;     // u32[32]
static constexpr size_t QR1_OFF   = 256;     // u32[32]
static constexpr size_t QLB_OFF   = 384;     // u32[32]  per-query list base
static constexpr size_t TOT1_OFF  = 1024;                                  // u32[R1*4096]
static constexpr size_t ZERO_BYTES = TOT1_OFF + (size_t)R1 * 4096 * 4;     // memset range (~263 KB)
static constexpr size_t TCNT_OFF  = ZERO_BYTES;                            // u32[NBLK_A*512] (fully written)
static constexpr size_t TCUR_OFF  = TCNT_OFF + (size_t)NBLK_A * 512 * 4;   // u32[512*CUR_STRIDE]
static constexpr size_t TBASE_OFF = TCUR_OFF + (size_t)512 * CUR_STRIDE * 4; // u32[512]
static constexpr size_t QLC_OFF   = TBASE_OFF + 512 * 4;                   // u32[NQ*CUR_STRIDE]
static constexpr size_t UNION_OFF = (QLC_OFF + (size_t)NQ * CUR_STRIDE * 4 + 255) & ~255ull;
// lists (u32[NPIX]) and pairs (uint2[NPIX]) share UNION region: lists dead before scatter

// ---- geometry helper: target pixel index, or -1 if dropped (flow-only) ----
__device__ __forceinline__ int target_of(int y, int x, float fx, float fy) {
    int ty = (int)rintf((float)y + fy);  // rintf = round-half-even = jnp.round
    int tx = (int)rintf((float)x + fx);
    if (ty < 0) ty += HH;                // JAX normalizes negative indices once
    if (tx < 0) tx += WW;
    if ((unsigned)ty >= (unsigned)HH || (unsigned)tx >= (unsigned)WW) return -1;
    return ty * WW + tx;
}

// ---- level 1: LDS 4096-bin histogram of bits[31:20] + per-tile target counts ----
__global__ __launch_bounds__(256) void k_histA_cnt(const float* __restrict__ depth,
                                                   const float* __restrict__ flow,
                                                   u32* __restrict__ tot1,
                                                   u32* __restrict__ tcnt) {
    __shared__ u32 h[4096];
    __shared__ u32 tc[512];
    for (int j = threadIdx.x; j < 4096; j += 256) h[j] = 0;
    for (int j = threadIdx.x; j < 512; j += 256) tc[j] = 0;
    __syncthreads();
    const int nvec = NPIX / 4;
    for (int v = blockIdx.x * 256 + threadIdx.x; v < nvec; v += gridDim.x * 256) {
        int i = v * 4;
        float4 d4 = ((const float4*)depth)[v];
        float4 fa = ((const float4*)flow)[v * 2];
        float4 fb = ((const float4*)flow)[v * 2 + 1];
        int y = i / WW, x0 = i - y * WW;   // 4-group never crosses a row (WW%4==0)
        float dd[4] = {d4.x, d4.y, d4.z, d4.w};
        float fx[4] = {fa.x, fa.z, fb.x, fb.z};
        float fy[4] = {fa.y, fa.w, fb.y, fb.w};
        #pragma unroll
        for (int j = 0; j < 4; ++j) {
            if (dd[j] != 100.0f)                                   // sentinel excluded
                atomicAdd(&h[__float_as_uint(dd[j]) >> 20], 1u);   // d>0 -> monotonic bits
            int t = target_of(y, x0 + j, fx[j], fy[j]);
            if (t >= 0) {
                int ty = t / WW, tx = t - ty * WW;
                atomicAdd(&tc[(ty >> 6) * TCX + (tx >> 6)], 1u);
            }
        }
    }
    __syncthreads();
    u32 rep = blockIdx.x & (R1 - 1);
    for (int j = threadIdx.x; j < 4096; j += 256) {
        u32 v = h[j];
        if (v) atomicAdd(&tot1[rep * 4096 + j], v);   // ~80 occupied bins/block
    }
    for (int j = threadIdx.x; j < 512; j += 256)
        tcnt[blockIdx.x * 512 + j] = tc[j];           // non-atomic replica write
}

// ---- level-1 select + per-query list bases + tile prefix-sum ----
__global__ __launch_bounds__(1024) void k_selA(const u32* __restrict__ tot1,
                                               const int* __restrict__ splitp,
                                               const u32* __restrict__ tcnt,
                                               u32* __restrict__ qb1, u32* __restrict__ qr1,
                                               u32* __restrict__ qlbase, u32* __restrict__ qlcur,
                                               u32* __restrict__ tbase, u32* __restrict__ tcur) {
    __shared__ u32 part[1024];
    __shared__ u32 qbS[NQ], qcS[NQ];
    __shared__ u32 totalsh;
    int tid = threadIdx.x;
    int split = *splitp;
    int base = tid * 4;
    u32 cc[4] = {0, 0, 0, 0};
    for (int r = 0; r < R1; ++r)
        for (int j = 0; j < 4; ++j) cc[j] += tot1[r * 4096 + base + j];
    u32 local = cc[0] + cc[1] + cc[2] + cc[3];
    part[tid] = local;
    __syncthreads();
    for (int off = 1; off < 1024; off <<= 1) {
        u32 v = (tid >= off) ? part[tid - off] : 0;
        __syncthreads();
        part[tid] += v;
        __syncthreads();
    }
    if (tid == 1023) totalsh = part[1023];
    __syncthreads();
    u32 l = totalsh;                 // valid-pixel count = histogram sum
    u32 step = l / (u32)split;
    u32 cum = part[tid] - local;     // exclusive prefix of this thread's 4 bins
    for (int j = 0; j < 4; ++j) {
        u32 c = cc[j];
        if (c) {
            for (int q = 0; q <= split; ++q) {
                u32 r = (q < split) ? (u32)q * step : l - 1u;
                if (r >= cum && r < cum + c) {
                    qb1[q] = (u32)(base + j);
                    qr1[q] = r - cum;
                    qbS[q] = (u32)(base + j);
                    qcS[q] = c;
                }
            }
        }
        cum += c;
    }
    __syncthreads();
    if (tid == 0) {      // per-query compacted-list bases (dedupe shared bins)
        u32 run = 0, prev = 0;
        for (int q = 0; q <= split; ++q) {
            u32 b;
            if (q > 0 && qbS[q] == qbS[q - 1]) b = prev;
            else { b = run; run += qcS[q]; }
            prev = b;
            qlbase[q] = b;
            qlcur[q * CUR_STRIDE] = b;
        }
    }
    __syncthreads();
    // ---- tile counts: reduce NBLK_A replicas, prefix-sum -> base & cursor ----
    u32 tval = 0;
    if (tid < 512)
        for (int b = 0; b < NBLK_A; ++b) tval += tcnt[b * 512 + tid];
    part[tid] = tval;
    __syncthreads();
    for (int off = 1; off < 1024; off <<= 1) {
        u32 v = (tid >= off) ? part[tid - off] : 0;
        __syncthreads();
        part[tid] += v;
        __syncthreads();
    }
    if (tid < 512) {
        u32 b = part[tid] - tval;
        tbase[tid] = b;
        tcur[tid * CUR_STRIDE] = b;
    }
}

// ---- compact: append low-20-bit keys of pixels in query bins to per-query lists ----
__global__ __launch_bounds__(256) void k_compact(const float* __restrict__ depth,
                                                 const int* __restrict__ splitp,
                                                 const u32* __restrict__ qb1,
                                                 u32* __restrict__ qlcur,
                                                 u32* __restrict__ lists) {
    __shared__ u32 qb[NQ], cnt[NQ], basel[NQ];
    int tid = threadIdx.x;
    int split = *splitp;
    if (tid < NQ) {
        cnt[tid] = 0;
        qb[tid] = (tid <= split) ? qb1[tid] : 0xFFFFFFFFu;
    }
    __syncthreads();
    int v = blockIdx.x * 256 + tid;           // grid = NPIX/1024 blocks, 4 px/thread
    float4 d4 = ((const float4*)depth)[v];
    float dd[4] = {d4.x, d4.y, d4.z, d4.w};
    u32 bits[4];
    int mq[4];
    u32 loc[4];
    #pragma unroll
    for (int j = 0; j < 4; ++j) {
        bits[j] = __float_as_uint(dd[j]);
        mq[j] = -1;
        if (dd[j] != 100.0f) {
            u32 b1 = bits[j] >> 20;
            for (int q = 0; q <= split; ++q)
                if (qb[q] == b1) { mq[j] = q; break; }   // first match only (dedupe)
        }
        if (mq[j] >= 0) loc[j] = atomicAdd(&cnt[mq[j]], 1u);
    }
    __syncthreads();
    if (tid < NQ && cnt[tid]) basel[tid] = atomicAdd(&qlcur[tid * CUR_STRIDE], cnt[tid]);
    __syncthreads();
    #pragma unroll
    for (int j = 0; j < 4; ++j)
        if (mq[j] >= 0) lists[basel[mq[j]] + loc[j]] = bits[j] & 0xFFFFFu;
}

// ---- select: exact order statistic within each query's list (LDS hist x2) ----
__global__ __launch_bounds__(1024) void k_select(const int* __restrict__ splitp,
                                                 const u32* __restrict__ qb1,
                                                 const u32* __restrict__ qr1,
                                                 const u32* __restrict__ qlbase,
                                                 const u32* __restrict__ qlcur,
                                                 const u32* __restrict__ lists,
                                                 float* __restrict__ mids) {
    int q = blockIdx.x;
    int split = *splitp;
    if (q > split) return;
    int q0 = q;
    while (q0 > 0 && qb1[q0 - 1] == qb1[q]) --q0;   // owner of the shared list
    u32 b = qlbase[q], e = qlcur[q0 * CUR_STRIDE];
    __shared__ u32 hist[1024];
    __shared__ u32 part[1024];
    __shared__ u32 b2sh, r2sh;
    int tid = threadIdx.x;
    hist[tid] = 0;
    __syncthreads();
    for (u32 k = b + tid; k < e; k += 1024) atomicAdd(&hist[lists[k] >> 10], 1u);
    __syncthreads();
    u32 local = hist[tid];
    part[tid] = local;
    __syncthreads();
    for (int off = 1; off < 1024; off <<= 1) {
        u32 v = (tid >= off) ? part[tid - off] : 0;
        __syncthreads();
        part[tid] += v;
        __syncthreads();
    }
    u32 target = qr1[q];
    u32 cum = part[tid] - local;
    if (local && target >= cum && target < cum + local) { b2sh = (u32)tid; r2sh = target - cum; }
    __syncthreads();
    u32 b2 = b2sh, r2 = r2sh;
    hist[tid] = 0;
    __syncthreads();
    for (u32 k = b + tid; k < e; k += 1024) {
        u32 key = lists[k];
        if ((key >> 10) == b2) atomicAdd(&hist[key & 1023u], 1u);
    }
    __syncthreads();
    local = hist[tid];
    part[tid] = local;
    __syncthreads();
    for (int off = 1; off < 1024; off <<= 1) {
        u32 v = (tid >= off) ? part[tid - off] : 0;
        __syncthreads();
        part[tid] += v;
        __syncthreads();
    }
    cum = part[tid] - local;
    if (local && r2 >= cum && r2 < cum + local)
        mids[q] = __uint_as_float((qb1[q] << 20) | (b2 << 10) | (u32)tid);
}

// ---- scatter: (t, p) pairs into contiguous per-tile slots ----
__global__ __launch_bounds__(256) void k_scatter(const float* __restrict__ depth,
                                                 const float* __restrict__ flow,
                                                 const int* __restrict__ splitp,
                                                 const float* __restrict__ mids,
                                                 u32* __restrict__ tcur,
                                                 uint2* __restrict__ pairs) {
    __shared__ u32 cnt[512];
    __shared__ u32 basel[512];
    __shared__ float msh[NQ];
    int tid = threadIdx.x;
    int split = *splitp;
    if (tid < NQ) msh[tid] = (tid <= split) ? mids[tid] : 0.f;
    for (int j = tid; j < 512; j += 256) cnt[j] = 0;
    __syncthreads();
    int v = blockIdx.x * 256 + tid;           // grid = NPIX/1024 blocks, 4 px/thread
    int i = v * 4;
    float4 d4 = ((const float4*)depth)[v];
    float4 fa = ((const float4*)flow)[v * 2];
    float4 fb = ((const float4*)flow)[v * 2 + 1];
    int y = i / WW, x0 = i - y * WW;
    float dd[4] = {d4.x, d4.y, d4.z, d4.w};
    float fx[4] = {fa.x, fa.z, fb.x, fb.z};
    float fy[4] = {fa.y, fa.w, fb.y, fb.w};
    int tile[4], tt[4];
    u32 loc[4];
    #pragma unroll
    for (int j = 0; j < 4; ++j) {
        float d = dd[j];
        int rank = -1;
        for (int k = 1; k <= split; ++k)
            if (d >= msh[k - 1] && d < msh[k]) { rank = split - k; break; }
        tile[j] = -1;
        if (rank >= 0) {
            int t = target_of(y, x0 + j, fx[j], fy[j]);
            if (t >= 0) {
                int ty = t / WW, tx = t - ty * WW;
                tile[j] = (ty >> 6) * TCX + (tx >> 6);
                tt[j] = t;
                // far bins = low rank; within bin, last row-major source wins
                loc[j] = atomicAdd(&cnt[tile[j]], 1u);
                tt[j] = t;
                // stash priority in loc's sibling: recompute below
            }
        }
        // store rank in high bits of tile slot? keep simple: recompute p at write
        if (tile[j] >= 0) {
            // remember p via dd[] reuse: pack rank temporarily
            dd[j] = __uint_as_float((u32)rank * (u32)NPIX + (u32)(i + j) + 1u);
        }
    }
    __syncthreads();
    for (int j = tid; j < 512; j += 256) {
        u32 c = cnt[j];
        if (c) basel[j] = atomicAdd(&tcur[j * CUR_STRIDE], c);  // ~25 device atomics/block
    }
    __syncthreads();
    #pragma unroll
    for (int j = 0; j < 4; ++j)
        if (tile[j] >= 0)
            pairs[basel[tile[j]] + loc[j]] = make_uint2((u32)tt[j], __float_as_uint(dd[j]));
}

// ---- per-tile LDS z-buffer reduce + output write ----
__global__ __launch_bounds__(256) void k_tile_reduce(const uint2* __restrict__ pairs,
                                                     const u32* __restrict__ tbase,
                                                     const u32* __restrict__ tcur,
                                                     const float* __restrict__ img,
                                                     float* __restrict__ out) {
    __shared__ u32 zb[TS * TS];
    int tid = threadIdx.x;
    int tile = blockIdx.x;
    for (int c = tid; c < TS * TS; c += 256) zb[c] = 0;
    __syncthreads();
    int ty0 = (tile / TCX) << 6, tx0 = (tile % TCX) << 6;
    u32 b = tbase[tile], e = tcur[tile * CUR_STRIDE];
    for (u32 k = b + tid; k < e; k += 256) {
        uint2 pr = pairs[k];
        int t = (int)pr.x;
        int ty = t / WW, tx = t - ty * WW;
        atomicMax(&zb[((ty - ty0) << 6) | (tx - tx0)], pr.y);   // LDS
    }
    __syncthreads();
    for (int c = tid; c < TS * TS; c += 256) {
        int ty = ty0 + (c >> 6);
        if (ty >= HH) continue;
        int tx = tx0 + (c & 63);
        u32 p = zb[c];
        float r = 0.f, g = 0.f, bl = 0.f;
        if (p) {
            u32 src = (p - 1u) % (u32)NPIX;   // p-1 = rank*NPIX + src
            r  = img[src * 3 + 0];
            g  = img[src * 3 + 1];
            bl = img[src * 3 + 2];
        }
        int t = ty * WW + tx;
        out[t * 3 + 0] = r;
        out[t * 3 + 1] = g;
        out[t * 3 + 2] = bl;
    }
}

extern "C" void kernel_launch(void* const* d_in, const int* in_sizes, int n_in,
                              void* d_out, int out_size, void* d_ws, size_t ws_size,
                              hipStream_t stream) {
    const float* img    = (const float*)d_in[0];
    const float* flow   = (const float*)d_in[1];   // [1,H,W,2] flat == [H,W,2]
    const float* depth  = (const float*)d_in[2];
    const int*   splitp = (const int*)d_in[3];

    char* ws = (char*)d_ws;
    float* mids   = (float*)(ws + MIDS_OFF);
    u32*   qb1    = (u32*)(ws + QB1_OFF);
    u32*   qr1    = (u32*)(ws + QR1_OFF);
    u32*   qlbase = (u32*)(ws + QLB_OFF);
    u32*   tot1   = (u32*)(ws + TOT1_OFF);
    u32*   tcnt   = (u32*)(ws + TCNT_OFF);
    u32*   tcur   = (u32*)(ws + TCUR_OFF);
    u32*   tbase  = (u32*)(ws + TBASE_OFF);
    u32*   qlcur  = (u32*)(ws + QLC_OFF);
    u32*   lists  = (u32*)(ws + UNION_OFF);        // union with pairs (lists die first)
    uint2* pairs  = (uint2*)(ws + UNION_OFF);
    float* out    = (float*)d_out;

    // zero: header + level-1 histogram only (~263 KB)
    hipMemsetAsync(d_ws, 0, ZERO_BYTES, stream);

    int vblocks = NPIX / 1024;   // 2025 (4 px/thread kernels)
    k_histA_cnt  <<<NBLK_A, 256, 0, stream>>>(depth, flow, tot1, tcnt);
    k_selA       <<<1, 1024, 0, stream>>>(tot1, splitp, tcnt, qb1, qr1, qlbase, qlcur, tbase, tcur);
    k_compact    <<<vblocks, 256, 0, stream>>>(depth, splitp, qb1, qlcur, lists);
    k_select     <<<NQ, 1024, 0, stream>>>(splitp, qb1, qr1, qlbase, qlcur, lists, mids);
    k_scatter    <<<vblocks, 256, 0, stream>>>(depth, flow, splitp, mids, tcur, pairs);
    k_tile_reduce<<<NTILE, 256, 0, stream>>>(pairs, tbase, tcur, img, out);
}

// Round 6
// 147.971 us; speedup vs baseline: 1.4603x; 1.4603x over previous
//
#include <hip/hip_runtime.h>

typedef unsigned int u32;

static constexpr int HH = 1080, WW = 1920;
static constexpr int NPIX = HH * WW;           // 2,073,600
static constexpr int NQ = 17;                  // supports split <= 16 (actual 10)
static constexpr int NBLK_A = 256;             // grid-stride blocks for level-1 pass
static constexpr int R1 = 16;                  // replicas for level-1 bin merge
static constexpr int NCHUNK = 32;              // list chunks per query for select
static constexpr int TS = 64;                  // target tile size
static constexpr int TCX = WW / TS;            // 30
static constexpr int TCY = (HH + TS - 1) / TS; // 17
static constexpr int NTILE = TCX * TCY;        // 510 (padded to 512)
static constexpr int CUR_STRIDE = 16;          // cursor padding (1 per cache line)

// ---- workspace layout (bytes) ----
static constexpr size_t MIDS_OFF  = 0;       // float[32]
static constexpr size_t QB1_OFF   = 128;     // u32[32]
static constexpr size_t QR1_OFF   = 256;     // u32[32]
static constexpr size_t QLB_OFF   = 384;     // u32[32]  per-query list base
static constexpr size_t B2_OFF    = 512;     // u32[32]  selected 10-bit mid bin
static constexpr size_t R2_OFF    = 640;     // u32[32]  rank within mid bin
static constexpr size_t TOT1_OFF  = 1024;                                  // u32[R1*4096]
static constexpr size_t ZERO_BYTES = TOT1_OFF + (size_t)R1 * 4096 * 4;     // memset (~263 KB)
static constexpr size_t TCNT_OFF  = ZERO_BYTES;                            // u32[NBLK_A*512] fully written
static constexpr size_t TCUR_OFF  = TCNT_OFF + (size_t)NBLK_A * 512 * 4;   // u32[512*CUR_STRIDE]
static constexpr size_t TBASE_OFF = TCUR_OFF + (size_t)512 * CUR_STRIDE * 4; // u32[512]
static constexpr size_t QLC_OFF   = TBASE_OFF + 512 * 4;                   // u32[NQ*CUR_STRIDE]
static constexpr size_t GHIST_OFF = (QLC_OFF + (size_t)NQ * CUR_STRIDE * 4 + 255) & ~255ull;
static constexpr size_t UNION_OFF = (GHIST_OFF + (size_t)NQ * NCHUNK * 1024 * 4 + 255) & ~255ull;
// lists (u32[NPIX]) and pairs (uint2[NPIX]) share UNION: lists dead before scatter

// ---- geometry helper: target pixel index, or -1 if dropped (flow-only) ----
__device__ __forceinline__ int target_of(int y, int x, float fx, float fy) {
    int ty = (int)rintf((float)y + fy);  // rintf = round-half-even = jnp.round
    int tx = (int)rintf((float)x + fx);
    if (ty < 0) ty += HH;                // JAX normalizes negative indices once
    if (tx < 0) tx += WW;
    if ((unsigned)ty >= (unsigned)HH || (unsigned)tx >= (unsigned)WW) return -1;
    return ty * WW + tx;
}

// ---- level 1: LDS 4096-bin histogram of bits[31:20] + per-tile target counts ----
__global__ __launch_bounds__(256) void k_histA_cnt(const float* __restrict__ depth,
                                                   const float* __restrict__ flow,
                                                   u32* __restrict__ tot1,
                                                   u32* __restrict__ tcnt) {
    __shared__ u32 h[4096];
    __shared__ u32 tc[512];
    for (int j = threadIdx.x; j < 4096; j += 256) h[j] = 0;
    for (int j = threadIdx.x; j < 512; j += 256) tc[j] = 0;
    __syncthreads();
    const int nvec = NPIX / 4;
    for (int v = blockIdx.x * 256 + threadIdx.x; v < nvec; v += gridDim.x * 256) {
        int i = v * 4;
        float4 d4 = ((const float4*)depth)[v];
        float4 fa = ((const float4*)flow)[v * 2];
        float4 fb = ((const float4*)flow)[v * 2 + 1];
        int y = i / WW, x0 = i - y * WW;   // 4-group never crosses a row (WW%4==0)
        float dd[4] = {d4.x, d4.y, d4.z, d4.w};
        float fx[4] = {fa.x, fa.z, fb.x, fb.z};
        float fy[4] = {fa.y, fa.w, fb.y, fb.w};
        #pragma unroll
        for (int j = 0; j < 4; ++j) {
            if (dd[j] != 100.0f)                                   // sentinel excluded
                atomicAdd(&h[__float_as_uint(dd[j]) >> 20], 1u);   // d>0 -> monotonic bits
            int t = target_of(y, x0 + j, fx[j], fy[j]);
            if (t >= 0) {
                int ty = t / WW, tx = t - ty * WW;
                atomicAdd(&tc[(ty >> 6) * TCX + (tx >> 6)], 1u);
            }
        }
    }
    __syncthreads();
    u32 rep = blockIdx.x & (R1 - 1);
    for (int j = threadIdx.x; j < 4096; j += 256) {
        u32 v = h[j];
        if (v) atomicAdd(&tot1[rep * 4096 + j], v);   // ~80 occupied bins/block
    }
    for (int j = threadIdx.x; j < 512; j += 256)
        tcnt[blockIdx.x * 512 + j] = tc[j];           // non-atomic replica write
}

// ---- level-1 select + per-query list bases + tile prefix-sum ----
__global__ __launch_bounds__(1024) void k_selA(const u32* __restrict__ tot1,
                                               const int* __restrict__ splitp,
                                               const u32* __restrict__ tcnt,
                                               u32* __restrict__ qb1, u32* __restrict__ qr1,
                                               u32* __restrict__ qlbase, u32* __restrict__ qlcur,
                                               u32* __restrict__ tbase, u32* __restrict__ tcur) {
    __shared__ u32 part[1024];
    __shared__ u32 qbS[NQ], qcS[NQ];
    __shared__ u32 totalsh;
    int tid = threadIdx.x;
    int split = *splitp;
    int base = tid * 4;
    u32 cc[4] = {0, 0, 0, 0};
    for (int r = 0; r < R1; ++r)
        for (int j = 0; j < 4; ++j) cc[j] += tot1[r * 4096 + base + j];
    u32 local = cc[0] + cc[1] + cc[2] + cc[3];
    part[tid] = local;
    __syncthreads();
    for (int off = 1; off < 1024; off <<= 1) {
        u32 v = (tid >= off) ? part[tid - off] : 0;
        __syncthreads();
        part[tid] += v;
        __syncthreads();
    }
    if (tid == 1023) totalsh = part[1023];
    __syncthreads();
    u32 l = totalsh;                 // valid-pixel count = histogram sum
    u32 step = l / (u32)split;
    u32 cum = part[tid] - local;     // exclusive prefix of this thread's 4 bins
    for (int j = 0; j < 4; ++j) {
        u32 c = cc[j];
        if (c) {
            for (int q = 0; q <= split; ++q) {
                u32 r = (q < split) ? (u32)q * step : l - 1u;
                if (r >= cum && r < cum + c) {
                    qb1[q] = (u32)(base + j);
                    qr1[q] = r - cum;
                    qbS[q] = (u32)(base + j);
                    qcS[q] = c;
                }
            }
        }
        cum += c;
    }
    __syncthreads();
    if (tid == 0) {      // per-query compacted-list bases (dedupe shared bins)
        u32 run = 0, prev = 0;
        for (int q = 0; q <= split; ++q) {
            u32 b;
            if (q > 0 && qbS[q] == qbS[q - 1]) b = prev;
            else { b = run; run += qcS[q]; }
            prev = b;
            qlbase[q] = b;
            qlcur[q * CUR_STRIDE] = b;
        }
    }
    __syncthreads();
    // ---- tile counts: reduce NBLK_A replicas, prefix-sum -> base & cursor ----
    u32 tval = 0;
    if (tid < 512)
        for (int b = 0; b < NBLK_A; ++b) tval += tcnt[b * 512 + tid];
    part[tid] = tval;
    __syncthreads();
    for (int off = 1; off < 1024; off <<= 1) {
        u32 v = (tid >= off) ? part[tid - off] : 0;
        __syncthreads();
        part[tid] += v;
        __syncthreads();
    }
    if (tid < 512) {
        u32 b = part[tid] - tval;
        tbase[tid] = b;
        tcur[tid * CUR_STRIDE] = b;
    }
}

// ---- compact: append low-20-bit keys of pixels in query bins to per-query lists ----
__global__ __launch_bounds__(256) void k_compact(const float* __restrict__ depth,
                                                 const int* __restrict__ splitp,
                                                 const u32* __restrict__ qb1,
                                                 u32* __restrict__ qlcur,
                                                 u32* __restrict__ lists) {
    __shared__ u32 qb[NQ], cnt[NQ], basel[NQ];
    int tid = threadIdx.x;
    int split = *splitp;
    if (tid < NQ) {
        cnt[tid] = 0;
        qb[tid] = (tid <= split) ? qb1[tid] : 0xFFFFFFFFu;
    }
    __syncthreads();
    int v = blockIdx.x * 256 + tid;           // grid = NPIX/1024 blocks, 4 px/thread
    float4 d4 = ((const float4*)depth)[v];
    float dd[4] = {d4.x, d4.y, d4.z, d4.w};
    u32 bits[4];
    int mq[4];
    u32 loc[4];
    #pragma unroll
    for (int j = 0; j < 4; ++j) {
        bits[j] = __float_as_uint(dd[j]);
        mq[j] = -1;
        if (dd[j] != 100.0f) {
            u32 b1 = bits[j] >> 20;
            for (int q = 0; q <= split; ++q)
                if (qb[q] == b1) { mq[j] = q; break; }   // first match only (dedupe)
        }
        if (mq[j] >= 0) loc[j] = atomicAdd(&cnt[mq[j]], 1u);
    }
    __syncthreads();
    if (tid < NQ && cnt[tid]) basel[tid] = atomicAdd(&qlcur[tid * CUR_STRIDE], cnt[tid]);
    __syncthreads();
    #pragma unroll
    for (int j = 0; j < 4; ++j)
        if (mq[j] >= 0) lists[basel[mq[j]] + loc[j]] = bits[j] & 0xFFFFFu;
}

// ---- helper: owner query (first query sharing this query's hi-12 bin) ----
__device__ __forceinline__ int owner_of(int q, const u32* qb1) {
    int q0 = q;
    while (q0 > 0 && qb1[q0 - 1] == qb1[q]) --q0;
    return q0;
}

// ---- select phase 1a: chunked LDS hist of key bits[19:10] over each query's list ----
__global__ __launch_bounds__(256) void k_sel_hist1(const int* __restrict__ splitp,
                                                   const u32* __restrict__ qb1,
                                                   const u32* __restrict__ qlbase,
                                                   const u32* __restrict__ qlcur,
                                                   const u32* __restrict__ lists,
                                                   u32* __restrict__ ghist) {
    int q = blockIdx.x >> 5, c = blockIdx.x & (NCHUNK - 1);
    if (q > *splitp) return;
    int q0 = owner_of(q, qb1);
    u32 b = qlbase[q0];
    u32 len = qlcur[q0 * CUR_STRIDE] - b;
    u32 lo = b + (u32)(((unsigned long long)len * (u32)c) >> 5);
    u32 hi = b + (u32)(((unsigned long long)len * (u32)(c + 1)) >> 5);
    __shared__ u32 h[1024];
    int tid = threadIdx.x;
    for (int j = tid; j < 1024; j += 256) h[j] = 0;
    __syncthreads();
    for (u32 k = lo + tid; k < hi; k += 256) atomicAdd(&h[lists[k] >> 10], 1u);
    __syncthreads();
    for (int j = tid; j < 1024; j += 256) ghist[(q * NCHUNK + c) * 1024 + j] = h[j];
}

// ---- select phase 1b: reduce chunks, scan -> (b2, r2) per query ----
__global__ __launch_bounds__(1024) void k_sel_red1(const int* __restrict__ splitp,
                                                   const u32* __restrict__ qr1,
                                                   const u32* __restrict__ ghist,
                                                   u32* __restrict__ b2o, u32* __restrict__ r2o) {
    int q = blockIdx.x;
    if (q > *splitp) return;
    __shared__ u32 part[1024];
    int tid = threadIdx.x;
    u32 local = 0;
    for (int c = 0; c < NCHUNK; ++c) local += ghist[(q * NCHUNK + c) * 1024 + tid];
    part[tid] = local;
    __syncthreads();
    for (int off = 1; off < 1024; off <<= 1) {
        u32 v = (tid >= off) ? part[tid - off] : 0;
        __syncthreads();
        part[tid] += v;
        __syncthreads();
    }
    u32 target = qr1[q];
    u32 cum = part[tid] - local;
    if (local && target >= cum && target < cum + local) {
        b2o[q] = (u32)tid;
        r2o[q] = target - cum;
    }
}

// ---- select phase 2a: chunked LDS hist of low 10 bits, restricted to b2 ----
__global__ __launch_bounds__(256) void k_sel_hist2(const int* __restrict__ splitp,
                                                   const u32* __restrict__ qb1,
                                                   const u32* __restrict__ qlbase,
                                                   const u32* __restrict__ qlcur,
                                                   const u32* __restrict__ b2o,
                                                   const u32* __restrict__ lists,
                                                   u32* __restrict__ ghist) {
    int q = blockIdx.x >> 5, c = blockIdx.x & (NCHUNK - 1);
    if (q > *splitp) return;
    int q0 = owner_of(q, qb1);
    u32 b = qlbase[q0];
    u32 len = qlcur[q0 * CUR_STRIDE] - b;
    u32 lo = b + (u32)(((unsigned long long)len * (u32)c) >> 5);
    u32 hi = b + (u32)(((unsigned long long)len * (u32)(c + 1)) >> 5);
    u32 b2 = b2o[q];
    __shared__ u32 h[1024];
    int tid = threadIdx.x;
    for (int j = tid; j < 1024; j += 256) h[j] = 0;
    __syncthreads();
    for (u32 k = lo + tid; k < hi; k += 256) {
        u32 key = lists[k];
        if ((key >> 10) == b2) atomicAdd(&h[key & 1023u], 1u);
    }
    __syncthreads();
    for (int j = tid; j < 1024; j += 256) ghist[(q * NCHUNK + c) * 1024 + j] = h[j];
}

// ---- select phase 2b: reduce chunks, scan -> exact order-statistic floats ----
__global__ __launch_bounds__(1024) void k_sel_red2(const int* __restrict__ splitp,
                                                   const u32* __restrict__ qb1,
                                                   const u32* __restrict__ b2o,
                                                   const u32* __restrict__ r2o,
                                                   const u32* __restrict__ ghist,
                                                   float* __restrict__ mids) {
    int q = blockIdx.x;
    if (q > *splitp) return;
    __shared__ u32 part[1024];
    int tid = threadIdx.x;
    u32 local = 0;
    for (int c = 0; c < NCHUNK; ++c) local += ghist[(q * NCHUNK + c) * 1024 + tid];
    part[tid] = local;
    __syncthreads();
    for (int off = 1; off < 1024; off <<= 1) {
        u32 v = (tid >= off) ? part[tid - off] : 0;
        __syncthreads();
        part[tid] += v;
        __syncthreads();
    }
    u32 target = r2o[q];
    u32 cum = part[tid] - local;
    if (local && target >= cum && target < cum + local)
        mids[q] = __uint_as_float((qb1[q] << 20) | (b2o[q] << 10) | (u32)tid);
}

// ---- scatter: (t, p) pairs into contiguous per-tile slots ----
__global__ __launch_bounds__(256) void k_scatter(const float* __restrict__ depth,
                                                 const float* __restrict__ flow,
                                                 const int* __restrict__ splitp,
                                                 const float* __restrict__ mids,
                                                 u32* __restrict__ tcur,
                                                 uint2* __restrict__ pairs) {
    __shared__ u32 cnt[512];
    __shared__ u32 basel[512];
    __shared__ float msh[NQ];
    int tid = threadIdx.x;
    int split = *splitp;
    if (tid < NQ) msh[tid] = (tid <= split) ? mids[tid] : 0.f;
    for (int j = tid; j < 512; j += 256) cnt[j] = 0;
    __syncthreads();
    int v = blockIdx.x * 256 + tid;           // grid = NPIX/1024 blocks, 4 px/thread
    int i = v * 4;
    float4 d4 = ((const float4*)depth)[v];
    float4 fa = ((const float4*)flow)[v * 2];
    float4 fb = ((const float4*)flow)[v * 2 + 1];
    int y = i / WW, x0 = i - y * WW;
    float dd[4] = {d4.x, d4.y, d4.z, d4.w};
    float fx[4] = {fa.x, fa.z, fb.x, fb.z};
    float fy[4] = {fa.y, fa.w, fb.y, fb.w};
    int tile[4], tt[4];
    u32 pp[4], loc[4];
    #pragma unroll
    for (int j = 0; j < 4; ++j) {
        float d = dd[j];
        int rank = -1;
        for (int k = 1; k <= split; ++k)
            if (d >= msh[k - 1] && d < msh[k]) { rank = split - k; break; }
        tile[j] = -1;
        if (rank >= 0) {
            int t = target_of(y, x0 + j, fx[j], fy[j]);
            if (t >= 0) {
                int ty = t / WW, tx = t - ty * WW;
                tile[j] = (ty >> 6) * TCX + (tx >> 6);
                tt[j] = t;
                // far bins = low rank; within bin, last row-major source wins
                pp[j] = (u32)rank * (u32)NPIX + (u32)(i + j) + 1u;
                loc[j] = atomicAdd(&cnt[tile[j]], 1u);   // LDS
            }
        }
    }
    __syncthreads();
    for (int j = tid; j < 512; j += 256) {
        u32 c = cnt[j];
        if (c) basel[j] = atomicAdd(&tcur[j * CUR_STRIDE], c);  // ~25 device atomics/block
    }
    __syncthreads();
    #pragma unroll
    for (int j = 0; j < 4; ++j)
        if (tile[j] >= 0)
            pairs[basel[tile[j]] + loc[j]] = make_uint2((u32)tt[j], pp[j]);
}

// ---- per-tile LDS z-buffer reduce + output write ----
__global__ __launch_bounds__(256) void k_tile_reduce(const uint2* __restrict__ pairs,
                                                     const u32* __restrict__ tbase,
                                                     const u32* __restrict__ tcur,
                                                     const float* __restrict__ img,
                                                     float* __restrict__ out) {
    __shared__ u32 zb[TS * TS];
    int tid = threadIdx.x;
    int tile = blockIdx.x;
    for (int c = tid; c < TS * TS; c += 256) zb[c] = 0;
    __syncthreads();
    int ty0 = (tile / TCX) << 6, tx0 = (tile % TCX) << 6;
    u32 b = tbase[tile], e = tcur[tile * CUR_STRIDE];
    for (u32 k = b + tid; k < e; k += 256) {
        uint2 pr = pairs[k];
        int t = (int)pr.x;
        int ty = t / WW, tx = t - ty * WW;
        atomicMax(&zb[((ty - ty0) << 6) | (tx - tx0)], pr.y);   // LDS
    }
    __syncthreads();
    for (int c = tid; c < TS * TS; c += 256) {
        int ty = ty0 + (c >> 6);
        if (ty >= HH) continue;
        int tx = tx0 + (c & 63);
        u32 p = zb[c];
        float r = 0.f, g = 0.f, bl = 0.f;
        if (p) {
            u32 src = (p - 1u) % (u32)NPIX;   // p-1 = rank*NPIX + src
            r  = img[src * 3 + 0];
            g  = img[src * 3 + 1];
            bl = img[src * 3 + 2];
        }
        int t = ty * WW + tx;
        out[t * 3 + 0] = r;
        out[t * 3 + 1] = g;
        out[t * 3 + 2] = bl;
    }
}

extern "C" void kernel_launch(void* const* d_in, const int* in_sizes, int n_in,
                              void* d_out, int out_size, void* d_ws, size_t ws_size,
                              hipStream_t stream) {
    const float* img    = (const float*)d_in[0];
    const float* flow   = (const float*)d_in[1];   // [1,H,W,2] flat == [H,W,2]
    const float* depth  = (const float*)d_in[2];
    const int*   splitp = (const int*)d_in[3];

    char* ws = (char*)d_ws;
    float* mids   = (float*)(ws + MIDS_OFF);
    u32*   qb1    = (u32*)(ws + QB1_OFF);
    u32*   qr1    = (u32*)(ws + QR1_OFF);
    u32*   qlbase = (u32*)(ws + QLB_OFF);
    u32*   b2o    = (u32*)(ws + B2_OFF);
    u32*   r2o    = (u32*)(ws + R2_OFF);
    u32*   tot1   = (u32*)(ws + TOT1_OFF);
    u32*   tcnt   = (u32*)(ws + TCNT_OFF);
    u32*   tcur   = (u32*)(ws + TCUR_OFF);
    u32*   tbase  = (u32*)(ws + TBASE_OFF);
    u32*   qlcur  = (u32*)(ws + QLC_OFF);
    u32*   ghist  = (u32*)(ws + GHIST_OFF);
    u32*   lists  = (u32*)(ws + UNION_OFF);        // union with pairs (lists die first)
    uint2* pairs  = (uint2*)(ws + UNION_OFF);
    float* out    = (float*)d_out;

    // zero: header + level-1 histogram only (~263 KB)
    hipMemsetAsync(d_ws, 0, ZERO_BYTES, stream);

    int vblocks = NPIX / 1024;   // 2025 (4 px/thread kernels)
    k_histA_cnt  <<<NBLK_A, 256, 0, stream>>>(depth, flow, tot1, tcnt);
    k_selA       <<<1, 1024, 0, stream>>>(tot1, splitp, tcnt, qb1, qr1, qlbase, qlcur, tbase, tcur);
    k_compact    <<<vblocks, 256, 0, stream>>>(depth, splitp, qb1, qlcur, lists);
    k_sel_hist1  <<<NQ * NCHUNK, 256, 0, stream>>>(splitp, qb1, qlbase, qlcur, lists, ghist);
    k_sel_red1   <<<NQ, 1024, 0, stream>>>(splitp, qr1, ghist, b2o, r2o);
    k_sel_hist2  <<<NQ * NCHUNK, 256, 0, stream>>>(splitp, qb1, qlbase, qlcur, b2o, lists, ghist);
    k_sel_red2   <<<NQ, 1024, 0, stream>>>(splitp, qb1, b2o, r2o, ghist, mids);
    k_scatter    <<<vblocks, 256, 0, stream>>>(depth, flow, splitp, mids, tcur, pairs);
    k_tile_reduce<<<NTILE, 256, 0, stream>>>(pairs, tbase, tcur, img, out);
}